// Round 2
// baseline (986.418 us; speedup 1.0000x reference)
//
#include <hip/hip_runtime.h>

// Problem constants (from reference)
#define NB   2048   // batch
#define S    256    // scratchpad slots
#define D    64     // feature dim
#define H    4      // heads
#define HD   16     // head dim
#define HID  128    // MLP hidden
#define TPB  256
#define SCALEF 10.0f

__device__ __forceinline__ float wred_max(float v){
#pragma unroll
  for (int m = 32; m >= 1; m >>= 1) v = fmaxf(v, __shfl_xor(v, m, 64));
  return v;
}
__device__ __forceinline__ float wred_sum(float v){
#pragma unroll
  for (int m = 32; m >= 1; m >>= 1) v += __shfl_xor(v, m, 64);
  return v;
}
// extract component h (wave-uniform runtime index) without scratch spill
__device__ __forceinline__ float pick4(float4 f, int h){
  float r = f.x;
  r = (h == 1) ? f.y : r;
  r = (h == 2) ? f.z : r;
  r = (h == 3) ? f.w : r;
  return r;
}

__global__ __launch_bounds__(TPB, 2)
void engine_kernel(const float* __restrict__ sp_init,
                   const float* __restrict__ ptr_init,
                   const float* __restrict__ wq, const float* __restrict__ bq,
                   const float* __restrict__ wk, const float* __restrict__ bk,
                   const float* __restrict__ wv, const float* __restrict__ bv,
                   const float* __restrict__ wo, const float* __restrict__ bo,
                   const float* __restrict__ ww, const float* __restrict__ bw,
                   const float* __restrict__ aw1, const float* __restrict__ ab1,
                   const float* __restrict__ aw2, const float* __restrict__ ab2,
                   const int*   __restrict__ nsteps,
                   float* __restrict__ out)
{
  // sp padded to stride 65: bank = (s + d) % 32 for element [s][d] -> <=2-way
  // conflicts for both access patterns we use (lanes-across-d, per-lane-row).
  __shared__ float  sp[S][D + 1];        // 66560 B
  __shared__ float4 attnT[S];            //  4096 B  (scores then attn, packed by head)
  __shared__ float  addrv[S];            //  1024 B  (addr_r, later addr_w)
  __shared__ float4 qkT[D];              //  1024 B  (qk per head, packed)
  __shared__ __align__(16) float hidden[HID];  // 512 B
  __shared__ float  parth[4][4][D];      //  4096 B  (partial-reduce scratch)
  __shared__ float  regv[D], qhv[D], readf[D], readv[D], wvalv[D]; // 1280 B
  __shared__ float  ctxv[H][D];          //  1024 B
  __shared__ float  qbv[H];
  __shared__ float  red[8];
  // total ~79.6 KB -> 2 blocks/CU (LDS-capped; VGPR budget 256 at 2 waves/EU)

  const int tid  = threadIdx.x;
  const int wid  = tid >> 6;
  const int lane = tid & 63;

  // a_w2 column for this thread, resident in VGPRs for the whole kernel.
  // Removes 128 KB/block/step of L2 re-reads (2.1 GB total) from the serial
  // dependency chain. Fully-unrolled static indexing -> stays in registers.
  float awcol[HID];
#pragma unroll
  for (int k = 0; k < HID; ++k) awcol[k] = aw2[k * S + tid];

  // stage scratchpad_init (broadcast across blocks -> L2/L3 served)
  for (int i = tid; i < S * D / 4; i += TPB) {
    float4 v = reinterpret_cast<const float4*>(sp_init)[i];
    int flat = i << 2;
    int s = flat >> 6, d = flat & 63;
    sp[s][d + 0] = v.x; sp[s][d + 1] = v.y; sp[s][d + 2] = v.z; sp[s][d + 3] = v.w;
  }
  float p0 = ptr_init[0];
  const int T = *nsteps;
  const float posq = (float)tid * (1.0f / 255.0f);  // linspace(0,1,256)[tid]
  __syncthreads();

  for (int t = 0; t < T; ++t) {
    // ---- P1: addr_r = softmax(-|pos - p0| * SCALE) over s
    {
      float a = -fabsf(posq - p0) * SCALEF;
      float m = wred_max(a);
      if (lane == 0) red[wid] = m;
      __syncthreads();
      m = fmaxf(fmaxf(red[0], red[1]), fmaxf(red[2], red[3]));
      float e = expf(a - m);
      float ss = wred_sum(e);
      if (lane == 0) red[4 + wid] = ss;
      __syncthreads();
      ss = red[4] + red[5] + red[6] + red[7];
      addrv[tid] = e / ss;
    }
    __syncthreads();

    // ---- P2: regv = addr_r @ sp   (thread (d=lane, g=wid) over 64 s each)
    {
      const int d = lane, s0 = wid * 64;
      float acc = 0.f;
#pragma unroll 8
      for (int i = 0; i < 64; ++i) acc += addrv[s0 + i] * sp[s0 + i][d];
      parth[wid][0][d] = acc;
    }
    __syncthreads();
    if (tid < 64)
      regv[tid] = parth[0][0][tid] + parth[1][0][tid] + parth[2][0][tid] + parth[3][0][tid];
    __syncthreads();

    // ---- P3: qh = regv @ wq + bq
    {
      const int j = lane, g = wid;
      float acc = 0.f;
#pragma unroll
      for (int i = 0; i < 16; ++i) { int e2 = g * 16 + i; acc += regv[e2] * wq[e2 * 64 + j]; }
      parth[g][0][j] = acc;
    }
    __syncthreads();
    if (tid < 64)
      qhv[tid] = bq[tid] + parth[0][0][tid] + parth[1][0][tid] + parth[2][0][tid] + parth[3][0][tid];
    __syncthreads();

    // ---- P4: qk[h][e] = sum_j wk[e][16h+j]*qh[16h+j];  qb[h] = qh_h . bk_h
    {
      const int h = wid, e2 = lane;
      float acc = 0.f;
#pragma unroll
      for (int j = 0; j < 16; ++j) acc += wk[e2 * 64 + h * 16 + j] * qhv[h * 16 + j];
      ((float*)qkT)[e2 * 4 + h] = acc;
      if (tid < 4) {
        float qb = 0.f;
#pragma unroll
        for (int j = 0; j < 16; ++j) qb += qhv[tid * 16 + j] * bk[tid * 16 + j];
        qbv[tid] = qb;
      }
    }
    __syncthreads();

    // ---- P5: scores[h][s] = (sp[s].qk[h] + qb[h]) * 0.25   (thread s owns row s)
    {
      float a0 = qbv[0], a1 = qbv[1], a2 = qbv[2], a3 = qbv[3];
#pragma unroll 8
      for (int e2 = 0; e2 < 64; ++e2) {
        float v = sp[tid][e2];
        float4 qk = qkT[e2];                 // broadcast b128
        a0 += v * qk.x; a1 += v * qk.y; a2 += v * qk.z; a3 += v * qk.w;
      }
      attnT[tid] = make_float4(a0 * 0.25f, a1 * 0.25f, a2 * 0.25f, a3 * 0.25f);
    }
    __syncthreads();
    // per-head softmax: wave h owns head h, lane i covers s = i, i+64, i+128, i+192
    // (cross-wave float4 reads overlap others' word-writes; LDS is word-atomic
    //  and the overlapped component is discarded by pick4 -> safe)
    {
      const int h = wid, i = lane;
      float4 f0 = attnT[i], f1 = attnT[i + 64], f2 = attnT[i + 128], f3 = attnT[i + 192];
      float v0 = pick4(f0, h), v1 = pick4(f1, h), v2 = pick4(f2, h), v3 = pick4(f3, h);
      float mm = wred_max(fmaxf(fmaxf(v0, v1), fmaxf(v2, v3)));
      v0 = expf(v0 - mm); v1 = expf(v1 - mm); v2 = expf(v2 - mm); v3 = expf(v3 - mm);
      float sum = wred_sum(v0 + v1 + v2 + v3);
      float inv = 1.0f / sum;
      ((float*)attnT)[(i      ) * 4 + h] = v0 * inv;
      ((float*)attnT)[(i +  64) * 4 + h] = v1 * inv;
      ((float*)attnT)[(i + 128) * 4 + h] = v2 * inv;
      ((float*)attnT)[(i + 192) * 4 + h] = v3 * inv;
    }
    __syncthreads();

    // ---- P6: ctx[h] = attn[h] @ sp
    {
      const int d = lane, s0 = wid * 64;
      float a0 = 0, a1 = 0, a2 = 0, a3 = 0;
#pragma unroll 4
      for (int i = 0; i < 64; ++i) {
        int s = s0 + i;
        float v = sp[s][d];
        float4 at = attnT[s];                // broadcast b128
        a0 += at.x * v; a1 += at.y * v; a2 += at.z * v; a3 += at.w * v;
      }
      parth[wid][0][d] = a0; parth[wid][1][d] = a1; parth[wid][2][d] = a2; parth[wid][3][d] = a3;
    }
    __syncthreads();
    {
      const int h = wid, d = lane;
      ctxv[h][d] = parth[0][h][d] + parth[1][h][d] + parth[2][h][d] + parth[3][h][d];
    }
    __syncthreads();

    // ---- P7a: readf[f] = ctx[f>>4] . wv[:, f] + bv[f]   (V never materialized)
    {
      const int f = lane, g = wid, h = f >> 4;
      float acc = 0.f;
#pragma unroll
      for (int i = 0; i < 16; ++i) { int e2 = g * 16 + i; acc += ctxv[h][e2] * wv[e2 * 64 + f]; }
      parth[g][0][f] = acc;
    }
    __syncthreads();
    if (tid < 64)
      readf[tid] = bv[tid] + parth[0][0][tid] + parth[1][0][tid] + parth[2][0][tid] + parth[3][0][tid];
    __syncthreads();
    // ---- P7b: readv = readf @ wo + bo
    {
      const int c = lane, g = wid;
      float acc = 0.f;
#pragma unroll
      for (int i = 0; i < 16; ++i) { int f2 = g * 16 + i; acc += readf[f2] * wo[f2 * 64 + c]; }
      parth[g][1][c] = acc;
    }
    __syncthreads();
    if (tid < 64)
      readv[tid] = bo[tid] + parth[0][1][tid] + parth[1][1][tid] + parth[2][1][tid] + parth[3][1][tid];
    __syncthreads();

    // ---- P8: hidden = relu(readv @ aw1 + ab1)
    {
      const int k = tid & 127, g = tid >> 7;
      float acc = 0.f;
#pragma unroll 8
      for (int i = 0; i < 32; ++i) { int e2 = g * 32 + i; acc += readv[e2] * aw1[e2 * 128 + k]; }
      ((float*)parth)[g * 128 + k] = acc;
    }
    __syncthreads();
    if (tid < 128)
      hidden[tid] = fmaxf(ab1[tid] + ((float*)parth)[tid] + ((float*)parth)[128 + tid], 0.f);
    __syncthreads();

    // ---- P9: addr_w = softmax(hidden @ aw2 + ab2)   (aw2 in VGPRs, hidden via
    //          LDS b128 broadcast -> no global traffic in the dependency chain)
    {
      float acc = ab2[tid];
#pragma unroll
      for (int k = 0; k < HID; k += 4) {
        float4 hv = *reinterpret_cast<const float4*>(&hidden[k]);
        acc += hv.x * awcol[k] + hv.y * awcol[k + 1] + hv.z * awcol[k + 2] + hv.w * awcol[k + 3];
      }
      float mm = wred_max(acc);
      if (lane == 0) red[wid] = mm;
      __syncthreads();
      mm = fmaxf(fmaxf(red[0], red[1]), fmaxf(red[2], red[3]));
      float ee = expf(acc - mm);
      float ss = wred_sum(ee);
      if (lane == 0) red[4 + wid] = ss;
      __syncthreads();
      ss = red[4] + red[5] + red[6] + red[7];
      addrv[tid] = ee / ss;
    }
    __syncthreads();

    // ---- P10: wval = readv @ ww + bw
    {
      const int c = lane, g = wid;
      float acc = 0.f;
#pragma unroll
      for (int i = 0; i < 16; ++i) { int e2 = g * 16 + i; acc += readv[e2] * ww[e2 * 64 + c]; }
      parth[g][0][c] = acc;
    }
    __syncthreads();
    if (tid < 64)
      wvalv[tid] = bw[tid] + parth[0][0][tid] + parth[1][0][tid] + parth[2][0][tid] + parth[3][0][tid];
    __syncthreads();

    // ---- P11: sp = sp*(1-aw) + wval*aw   (thread s owns row s)
    {
      float aa = addrv[tid];
      float om = 1.0f - aa;
#pragma unroll 8
      for (int d = 0; d < 64; ++d)
        sp[tid][d] = sp[tid][d] * om + wvalv[d] * aa;
    }
    p0 = fminf(fmaxf(p0 + (1.0f / (float)S), 0.f), 1.f);
    __syncthreads();
  }

  // write sp -> out[b]   (coalesced float4)
  float* ob = out + (size_t)blockIdx.x * (S * D);
  for (int i = tid; i < S * D / 4; i += TPB) {
    int flat = i << 2, s = flat >> 6, d = flat & 63;
    ((float4*)ob)[i] = make_float4(sp[s][d], sp[s][d + 1], sp[s][d + 2], sp[s][d + 3]);
  }
}

extern "C" void kernel_launch(void* const* d_in, const int* in_sizes, int n_in,
                              void* d_out, int out_size, void* d_ws, size_t ws_size,
                              hipStream_t stream) {
  // input order: x(0) register_init(1) scratchpad_init(2) pointer_init(3)
  // wq(4) bq(5) wk(6) bk(7) wv(8) bv(9) wo(10) bo(11) w_write(12) b_write(13)
  // a_w1(14) a_b1(15) a_w2(16) a_b2(17) p_w1(18) p_b1(19) p_w2(20) p_b2(21) num_steps(22)
  // x, register_init, p_w1/p_b1/p_w2/p_b2 are dead for the output (sp).
  const float* sp_init  = (const float*)d_in[2];
  const float* ptr_init = (const float*)d_in[3];
  const float* wq = (const float*)d_in[4];
  const float* bq = (const float*)d_in[5];
  const float* wk = (const float*)d_in[6];
  const float* bk = (const float*)d_in[7];
  const float* wv = (const float*)d_in[8];
  const float* bv = (const float*)d_in[9];
  const float* wo = (const float*)d_in[10];
  const float* bo = (const float*)d_in[11];
  const float* ww = (const float*)d_in[12];
  const float* bw = (const float*)d_in[13];
  const float* aw1 = (const float*)d_in[14];
  const float* ab1 = (const float*)d_in[15];
  const float* aw2 = (const float*)d_in[16];
  const float* ab2 = (const float*)d_in[17];
  const int* nsteps = (const int*)d_in[22];
  float* out = (float*)d_out;

  engine_kernel<<<dim3(NB), dim3(TPB), 0, stream>>>(
      sp_init, ptr_init, wq, bq, wk, bk, wv, bv, wo, bo, ww, bw,
      aw1, ab1, aw2, ab2, nsteps, out);
}